// Round 5
// baseline (2029.052 us; speedup 1.0000x reference)
//
#include <hip/hip_runtime.h>
#include <hip/hip_cooperative_groups.h>
#include <math.h>

namespace cg = cooperative_groups;

#define Bdim 32
#define Cdim 256
#define Hdim 64
#define Wdim 64
#define HW   (Hdim * Wdim)          // 4096
#define KS   5
#define HID  64
#define E_LAMBDA 1e-4f

#define NBLK 512                    // 2 blocks/CU x 256 CUs — conservative co-residency
#define CPB  (Bdim * Cdim / NBLK)   // 16 channels per block per phase

// native clang vector type — required by __builtin_nontemporal_store
typedef float vfloat4 __attribute__((ext_vector_type(4)));

// fast sigmoid: native v_exp_f32 + v_rcp_f32 (abs err ~1e-6, threshold 8e-2)
__device__ __forceinline__ float sigmoidf(float v) {
    return __builtin_amdgcn_rcpf(1.0f + __expf(-v));
}

// agent(device)-scope scalar traffic for the [B,C] intermediates: per-XCD L2s
// are not cross-coherent; grid.sync orders execution, these order the data.
__device__ __forceinline__ void st_agent(float* p, float v) {
    __hip_atomic_store(p, v, __ATOMIC_RELEASE, __HIP_MEMORY_SCOPE_AGENT);
}
__device__ __forceinline__ float ld_agent(const float* p) {
    return __hip_atomic_load(p, __ATOMIC_ACQUIRE, __HIP_MEMORY_SCOPE_AGENT);
}

// ======================= fused cooperative kernel =========================
__global__ __launch_bounds__(256, 2) void fused_kernel(
        const float* __restrict__ x,
        const float* __restrict__ conv_w,
        const float* __restrict__ w1,
        const float* __restrict__ w2,
        float* __restrict__ out,
        float* __restrict__ mean_c,
        float* __restrict__ inv_c,
        float* __restrict__ ssum,
        float* __restrict__ eca,
        float* __restrict__ alpha) {
    cg::grid_group grid = cg::this_grid();
    const int t    = threadIdx.x;
    const int lane = t & 63;
    const int wid  = t >> 6;

    __shared__ float red[8];
    __shared__ float bcast[2];

    // ---------------- Phase 1: per-channel stats + SimAM GAP sum ----------
    for (int ch = 0; ch < CPB; ++ch) {
        const int bc = blockIdx.x * CPB + ch;
        const vfloat4* __restrict__ x4 = (const vfloat4*)(x + (size_t)bc * HW);

        vfloat4 v[4];
        float sum = 0.0f, sq = 0.0f;
#pragma unroll
        for (int i = 0; i < 4; ++i) {
            v[i] = x4[t + 256 * i];
            sum += v[i].x + v[i].y + v[i].z + v[i].w;
            sq  += v[i].x * v[i].x + v[i].y * v[i].y
                 + v[i].z * v[i].z + v[i].w * v[i].w;
        }
#pragma unroll
        for (int off = 32; off > 0; off >>= 1) {
            sum += __shfl_down(sum, off);
            sq  += __shfl_down(sq, off);
        }
        if (lane == 0) { red[wid] = sum; red[4 + wid] = sq; }
        __syncthreads();
        if (t == 0) {
            const float ts = red[0] + red[1] + red[2] + red[3];
            const float tq = red[4] + red[5] + red[6] + red[7];
            const float mn  = ts * (1.0f / HW);
            const float var = (tq - ts * ts * (1.0f / HW)) * (1.0f / (HW - 1));
            const float inv = 0.25f / (var + E_LAMBDA);
            st_agent(&mean_c[bc], mn);
            st_agent(&inv_c[bc], inv);
            bcast[0] = mn;
            bcast[1] = inv;
        }
        __syncthreads();
        const float mn  = bcast[0];
        const float inv = bcast[1];

        float p = 0.0f;
#pragma unroll
        for (int i = 0; i < 4; ++i) {
            float d;
            d = v[i].x - mn; p += v[i].x * sigmoidf(d * d * inv + 0.5f);
            d = v[i].y - mn; p += v[i].y * sigmoidf(d * d * inv + 0.5f);
            d = v[i].z - mn; p += v[i].z * sigmoidf(d * d * inv + 0.5f);
            d = v[i].w - mn; p += v[i].w * sigmoidf(d * d * inv + 0.5f);
        }
#pragma unroll
        for (int off = 32; off > 0; off >>= 1) p += __shfl_down(p, off);
        if (lane == 0) red[wid] = p;
        __syncthreads();
        if (t == 0) st_agent(&ssum[bc], red[0] + red[1] + red[2] + red[3]);
        __syncthreads();   // protect red/bcast before next channel
    }
    grid.sync();

    // ---------------- Phase 2: ECA gate + MLP alpha (blocks 0..31) --------
    if (blockIdx.x < Bdim) {
        const int b = blockIdx.x;
        const int c = t;
        __shared__ float m[Cdim];
        __shared__ float gap[Cdim];
        __shared__ float hid[HID];

        m[c] = ld_agent(&mean_c[b * Cdim + c]);
        __syncthreads();

        float acc = 0.0f;
#pragma unroll
        for (int k = 0; k < KS; ++k) {
            const int cc = c + k - (KS - 1) / 2;
            const float mv = (cc >= 0 && cc < Cdim) ? m[cc] : 0.0f;
            acc += conv_w[k] * mv;
        }
        const float gate = sigmoidf(acc);
        st_agent(&eca[b * Cdim + c], gate);
        gap[c] = gate * m[c] + ld_agent(&ssum[b * Cdim + c]) * (1.0f / HW);
        __syncthreads();

        if (c < HID) {
            float h = 0.0f;
            for (int i = 0; i < Cdim; ++i) h += gap[i] * w1[c * Cdim + i];
            hid[c] = fmaxf(h, 0.0f);
        }
        __syncthreads();

        float a = 0.0f;
#pragma unroll
        for (int j = 0; j < HID; ++j) a += hid[j] * w2[c * HID + j];
        st_agent(&alpha[b * Cdim + c], sigmoidf(a));
    }
    grid.sync();

    // ---------------- Phase 3: final elementwise blend --------------------
    for (int ch = 0; ch < CPB; ++ch) {
        const int bc = blockIdx.x * CPB + ch;
        const float mn  = ld_agent(&mean_c[bc]);
        const float inv = ld_agent(&inv_c[bc]);
        const float g   = ld_agent(&eca[bc]);
        const float a   = ld_agent(&alpha[bc]);
        const float one_minus_a_g = (1.0f - a) * g;

        const vfloat4* __restrict__ x4 = (const vfloat4*)(x + (size_t)bc * HW);
        vfloat4* __restrict__ o4 = (vfloat4*)(out + (size_t)bc * HW);
#pragma unroll
        for (int i = 0; i < 4; ++i) {
            const vfloat4 v = x4[t + 256 * i];
            vfloat4 r;
            float d;
            d = v.x - mn; r.x = v.x * (a * sigmoidf(d * d * inv + 0.5f) + one_minus_a_g);
            d = v.y - mn; r.y = v.y * (a * sigmoidf(d * d * inv + 0.5f) + one_minus_a_g);
            d = v.z - mn; r.z = v.z * (a * sigmoidf(d * d * inv + 0.5f) + one_minus_a_g);
            d = v.w - mn; r.w = v.w * (a * sigmoidf(d * d * inv + 0.5f) + one_minus_a_g);
            __builtin_nontemporal_store(r, &o4[t + 256 * i]);
        }
    }
}

// ======================= fallback: proven 3-kernel path ===================
__global__ __launch_bounds__(256) void stats_kernel(
        const float* __restrict__ x,
        float* __restrict__ mean_out,
        float* __restrict__ inv_out,
        float* __restrict__ ssum_out) {
    const int bc = blockIdx.x;
    const vfloat4* __restrict__ x4 = (const vfloat4*)(x + (size_t)bc * HW);
    const int t = threadIdx.x;

    vfloat4 v[4];
    float sum = 0.0f, sq = 0.0f;
#pragma unroll
    for (int i = 0; i < 4; ++i) {
        v[i] = x4[t + 256 * i];
        sum += v[i].x + v[i].y + v[i].z + v[i].w;
        sq  += v[i].x * v[i].x + v[i].y * v[i].y
             + v[i].z * v[i].z + v[i].w * v[i].w;
    }
#pragma unroll
    for (int off = 32; off > 0; off >>= 1) {
        sum += __shfl_down(sum, off);
        sq  += __shfl_down(sq, off);
    }
    __shared__ float red[8];
    __shared__ float bcast[2];
    const int lane = t & 63;
    const int wid  = t >> 6;
    if (lane == 0) { red[wid] = sum; red[4 + wid] = sq; }
    __syncthreads();
    if (t == 0) {
        const float ts = red[0] + red[1] + red[2] + red[3];
        const float tq = red[4] + red[5] + red[6] + red[7];
        const float mn  = ts * (1.0f / HW);
        const float var = (tq - ts * ts * (1.0f / HW)) * (1.0f / (HW - 1));
        mean_out[bc] = mn;
        inv_out[bc]  = 0.25f / (var + E_LAMBDA);
        bcast[0] = mn;
        bcast[1] = inv_out[bc];
    }
    __syncthreads();
    const float mn  = bcast[0];
    const float inv = bcast[1];

    float p = 0.0f;
#pragma unroll
    for (int i = 0; i < 4; ++i) {
        float d;
        d = v[i].x - mn; p += v[i].x * sigmoidf(d * d * inv + 0.5f);
        d = v[i].y - mn; p += v[i].y * sigmoidf(d * d * inv + 0.5f);
        d = v[i].z - mn; p += v[i].z * sigmoidf(d * d * inv + 0.5f);
        d = v[i].w - mn; p += v[i].w * sigmoidf(d * d * inv + 0.5f);
    }
#pragma unroll
    for (int off = 32; off > 0; off >>= 1) p += __shfl_down(p, off);
    if (lane == 0) red[wid] = p;
    __syncthreads();
    if (t == 0) ssum_out[bc] = red[0] + red[1] + red[2] + red[3];
}

__global__ __launch_bounds__(256) void gate_mlp_kernel(
        const float* __restrict__ mean_c,
        const float* __restrict__ ssum,
        const float* __restrict__ conv_w,
        const float* __restrict__ w1,
        const float* __restrict__ w2,
        float* __restrict__ eca_out,
        float* __restrict__ alpha_out) {
    const int b = blockIdx.x;
    const int c = threadIdx.x;
    __shared__ float m[Cdim];
    __shared__ float gap[Cdim];
    __shared__ float hid[HID];

    m[c] = mean_c[b * Cdim + c];
    __syncthreads();

    float acc = 0.0f;
#pragma unroll
    for (int k = 0; k < KS; ++k) {
        const int cc = c + k - (KS - 1) / 2;
        const float mv = (cc >= 0 && cc < Cdim) ? m[cc] : 0.0f;
        acc += conv_w[k] * mv;
    }
    const float gate = sigmoidf(acc);
    eca_out[b * Cdim + c] = gate;
    gap[c] = gate * m[c] + ssum[b * Cdim + c] * (1.0f / HW);
    __syncthreads();

    if (c < HID) {
        float h = 0.0f;
        for (int i = 0; i < Cdim; ++i) h += gap[i] * w1[c * Cdim + i];
        hid[c] = fmaxf(h, 0.0f);
    }
    __syncthreads();

    float a = 0.0f;
#pragma unroll
    for (int j = 0; j < HID; ++j) a += hid[j] * w2[c * HID + j];
    alpha_out[b * Cdim + c] = sigmoidf(a);
}

__global__ __launch_bounds__(256) void final_kernel(
        const float* __restrict__ x,
        const float* __restrict__ mean_c,
        const float* __restrict__ inv_c,
        const float* __restrict__ eca,
        const float* __restrict__ alpha,
        float* __restrict__ out) {
    const int bc = blockIdx.x;
    const float mn  = mean_c[bc];
    const float inv = inv_c[bc];
    const float g   = eca[bc];
    const float a   = alpha[bc];
    const float one_minus_a_g = (1.0f - a) * g;

    const vfloat4* __restrict__ x4 = (const vfloat4*)(x + (size_t)bc * HW);
    vfloat4* __restrict__ o4 = (vfloat4*)(out + (size_t)bc * HW);
    const int t = threadIdx.x;

#pragma unroll
    for (int i = 0; i < 4; ++i) {
        const vfloat4 v = x4[t + 256 * i];
        vfloat4 r;
        float d;
        d = v.x - mn; r.x = v.x * (a * sigmoidf(d * d * inv + 0.5f) + one_minus_a_g);
        d = v.y - mn; r.y = v.y * (a * sigmoidf(d * d * inv + 0.5f) + one_minus_a_g);
        d = v.z - mn; r.z = v.z * (a * sigmoidf(d * d * inv + 0.5f) + one_minus_a_g);
        d = v.w - mn; r.w = v.w * (a * sigmoidf(d * d * inv + 0.5f) + one_minus_a_g);
        __builtin_nontemporal_store(r, &o4[t + 256 * i]);
    }
}

extern "C" void kernel_launch(void* const* d_in, const int* in_sizes, int n_in,
                              void* d_out, int out_size, void* d_ws, size_t ws_size,
                              hipStream_t stream) {
    const float* x      = (const float*)d_in[0];
    const float* conv_w = (const float*)d_in[1];
    const float* w1     = (const float*)d_in[2];
    const float* w2     = (const float*)d_in[3];
    float* out = (float*)d_out;

    const int BC = Bdim * Cdim;   // 8192
    float* mean_c = (float*)d_ws;            // [BC]
    float* inv_c  = mean_c + BC;             // [BC]
    float* ssum   = inv_c + BC;              // [BC]
    float* eca    = ssum + BC;               // [BC]
    float* alpha  = eca + BC;                // [BC]

    void* args[] = {
        (void*)&x, (void*)&conv_w, (void*)&w1, (void*)&w2, (void*)&out,
        (void*)&mean_c, (void*)&inv_c, (void*)&ssum, (void*)&eca, (void*)&alpha
    };
    hipError_t err = hipLaunchCooperativeKernel((const void*)fused_kernel,
                                                dim3(NBLK), dim3(256), args, 0, stream);
    if (err != hipSuccess) {
        // deterministic fallback: proven 3-kernel path (R3, 259.9 us)
        stats_kernel<<<BC, 256, 0, stream>>>(x, mean_c, inv_c, ssum);
        gate_mlp_kernel<<<Bdim, 256, 0, stream>>>(mean_c, ssum, conv_w, w1, w2, eca, alpha);
        final_kernel<<<BC, 256, 0, stream>>>(x, mean_c, inv_c, eca, alpha, out);
    }
}